// Round 6
// baseline (8274.123 us; speedup 1.0000x reference)
//
#include <hip/hip_runtime.h>

typedef _Float16 f16;
typedef _Float16 f16x8 __attribute__((ext_vector_type(8)));
typedef unsigned short u16;
typedef u16 u16x8 __attribute__((ext_vector_type(8)));
typedef float f32x4 __attribute__((ext_vector_type(4)));

__device__ __forceinline__ f16x8 cvt8(f32x4 lo, f32x4 hi) {
    f16x8 h;
    h[0] = (f16)lo[0]; h[1] = (f16)lo[1]; h[2] = (f16)lo[2]; h[3] = (f16)lo[3];
    h[4] = (f16)hi[0]; h[5] = (f16)hi[1]; h[6] = (f16)hi[2]; h[7] = (f16)hi[3];
    return h;
}

// Sentinel: if workspace unusable, fill output with f32 1.0 (finite marker).
__global__ void fill_sentinel_f32(float* __restrict__ out, long long n) {
    long long i = (long long)blockIdx.x * blockDim.x + threadIdx.x;
    long long stride = (long long)gridDim.x * blockDim.x;
    for (; i < n; i += stride) out[i] = 1.0f;
}

// NT GEMM. Inputs are fp32 device buffers holding fp16-exact values.
// A [rows,K], B [cols,K]; C[r,c] = sum_k A[r,k]*B[c,k]. fp16 MFMA, f32 accum.
// FUSED (GEMM1): A=f32 (x), B0/B1=f32 (Wg,Wu), C=f16 H, epilogue silu(g)*u.
// !FUSED (GEMM2): A=f16 (H), B0=f32 (Wd), C=f32 out.
// 128x128 tile, BK=32, 256 threads (4 waves 2x2), wave -> 64x64 out.
template<bool FUSED>
__global__ __launch_bounds__(256)
void mlp_gemm(const void* __restrict__ Av, const float* __restrict__ B0,
              const float* __restrict__ B1, void* __restrict__ Cv,
              int K, int ldc, int nRow, int nCol) {
    __shared__ __align__(16) f16 smA[128 * 32];
    __shared__ __align__(16) f16 smB0[128 * 32];
    __shared__ __align__(16) f16 smB1[FUSED ? 128 * 32 : 8];

    // ---- block remap: 8 row-blocks share a B col-panel (L2 weight reuse) ----
    const int GROUP = 8;
    int lin  = blockIdx.x;
    int perG = GROUP * nCol;
    int g    = lin / perG;
    int rem  = lin - g * perG;
    int rowsInG = nRow - g * GROUP; if (rowsInG > GROUP) rowsInG = GROUP;
    int colB = rem / rowsInG;
    int rowB = g * GROUP + (rem - colB * rowsInG);

    const long long blockRow = (long long)rowB * 128;
    const long long blockCol = (long long)colB * 128;

    const int tid  = threadIdx.x;
    const int w    = tid >> 6;
    const int lane = tid & 63;
    const int waveM = w >> 1;
    const int waveN = w & 1;

    // ---- staging slots: slot = tid (+256); row = slot>>2, seg = slot&3 ----
    const int r0 = tid >> 2;          // 0..63
    const int s0 = tid & 3;           // col segment, 8 elems each
    // slot+256 -> row r0+64, same seg
    const float* gA_f32_0;
    const float* gA_f32_1;
    const f16*   gA_f16_0;
    const f16*   gA_f16_1;
    if constexpr (FUSED) {
        const float* A = (const float*)Av;
        gA_f32_0 = A + (blockRow + r0)      * (long long)K + s0 * 8;
        gA_f32_1 = A + (blockRow + r0 + 64) * (long long)K + s0 * 8;
        gA_f16_0 = nullptr; gA_f16_1 = nullptr;
    } else {
        const f16* A = (const f16*)Av;
        gA_f16_0 = A + (blockRow + r0)      * (long long)K + s0 * 8;
        gA_f16_1 = A + (blockRow + r0 + 64) * (long long)K + s0 * 8;
        gA_f32_0 = nullptr; gA_f32_1 = nullptr;
    }
    const float* gB0_0 = B0 + (blockCol + r0)      * (long long)K + s0 * 8;
    const float* gB0_1 = B0 + (blockCol + r0 + 64) * (long long)K + s0 * 8;
    const float* gB1_0 = FUSED ? (B1 + (blockCol + r0)      * (long long)K + s0 * 8) : nullptr;
    const float* gB1_1 = FUSED ? (B1 + (blockCol + r0 + 64) * (long long)K + s0 * 8) : nullptr;

    const int off0 = tid * 8;          // f16 element offset in [128][32] tile
    const int off1 = off0 + 2048;      // slot+256

    // ---- fragment offsets (16x16x32: row=lane&15, k=(lane>>4)*8) ----
    const int fr = lane & 15;
    const int fk = (lane >> 4) * 8;
    int offA[4], offB[4];
#pragma unroll
    for (int i = 0; i < 4; ++i) {
        offA[i] = (waveM * 64 + i * 16 + fr) * 32 + fk;
        offB[i] = (waveN * 64 + i * 16 + fr) * 32 + fk;
    }

    f32x4 acc0[4][4];
    f32x4 acc1[4][4];
#pragma unroll
    for (int mi = 0; mi < 4; ++mi)
#pragma unroll
        for (int ni = 0; ni < 4; ++ni) {
            acc0[mi][ni] = (f32x4){0.f, 0.f, 0.f, 0.f};
            if constexpr (FUSED) acc1[mi][ni] = (f32x4){0.f, 0.f, 0.f, 0.f};
        }

    const int ksteps = K >> 5;
    for (int kt = 0; kt < ksteps; ++kt) {
        // ---- issue global loads (latency hides under prev MFMA) ----
        f16x8 vA0, vA1, vB00, vB01, vB10, vB11;
        if constexpr (FUSED) {
            f32x4 a0l = *(const f32x4*)gA_f32_0;
            f32x4 a0h = *(const f32x4*)(gA_f32_0 + 4);
            f32x4 a1l = *(const f32x4*)gA_f32_1;
            f32x4 a1h = *(const f32x4*)(gA_f32_1 + 4);
            vA0 = cvt8(a0l, a0h);
            vA1 = cvt8(a1l, a1h);
            gA_f32_0 += 32; gA_f32_1 += 32;
        } else {
            vA0 = *(const f16x8*)gA_f16_0;
            vA1 = *(const f16x8*)gA_f16_1;
            gA_f16_0 += 32; gA_f16_1 += 32;
        }
        {
            f32x4 b0l = *(const f32x4*)gB0_0;
            f32x4 b0h = *(const f32x4*)(gB0_0 + 4);
            f32x4 b1l = *(const f32x4*)gB0_1;
            f32x4 b1h = *(const f32x4*)(gB0_1 + 4);
            vB00 = cvt8(b0l, b0h);
            vB01 = cvt8(b1l, b1h);
            gB0_0 += 32; gB0_1 += 32;
        }
        if constexpr (FUSED) {
            f32x4 c0l = *(const f32x4*)gB1_0;
            f32x4 c0h = *(const f32x4*)(gB1_0 + 4);
            f32x4 c1l = *(const f32x4*)gB1_1;
            f32x4 c1h = *(const f32x4*)(gB1_1 + 4);
            vB10 = cvt8(c0l, c0h);
            vB11 = cvt8(c1l, c1h);
            gB1_0 += 32; gB1_1 += 32;
        }

        __syncthreads();   // previous iteration's LDS reads complete

        *(f16x8*)(smA  + off0) = vA0;
        *(f16x8*)(smA  + off1) = vA1;
        *(f16x8*)(smB0 + off0) = vB00;
        *(f16x8*)(smB0 + off1) = vB01;
        if constexpr (FUSED) {
            *(f16x8*)(smB1 + off0) = vB10;
            *(f16x8*)(smB1 + off1) = vB11;
        }

        __syncthreads();   // tiles visible

        f16x8 aF[4], bF[4], b1F[4];
#pragma unroll
        for (int i = 0; i < 4; ++i) aF[i] = *(const f16x8*)(smA + offA[i]);
#pragma unroll
        for (int i = 0; i < 4; ++i) bF[i] = *(const f16x8*)(smB0 + offB[i]);
        if constexpr (FUSED) {
#pragma unroll
            for (int i = 0; i < 4; ++i) b1F[i] = *(const f16x8*)(smB1 + offB[i]);
        }

#pragma unroll
        for (int mi = 0; mi < 4; ++mi)
#pragma unroll
            for (int ni = 0; ni < 4; ++ni) {
                acc0[mi][ni] = __builtin_amdgcn_mfma_f32_16x16x32_f16(
                    aF[mi], bF[ni], acc0[mi][ni], 0, 0, 0);
                if constexpr (FUSED)
                    acc1[mi][ni] = __builtin_amdgcn_mfma_f32_16x16x32_f16(
                        aF[mi], b1F[ni], acc1[mi][ni], 0, 0, 0);
            }
    }

    // ---- epilogue: C/D layout col=lane&15, row=(lane>>4)*4+j ----
    const long long orBase = blockRow + waveM * 64 + ((lane >> 4) * 4);
    const long long ocBase = blockCol + waveN * 64 + fr;
#pragma unroll
    for (int mi = 0; mi < 4; ++mi)
#pragma unroll
        for (int ni = 0; ni < 4; ++ni)
#pragma unroll
            for (int j = 0; j < 4; ++j) {
                const long long idx =
                    (orBase + mi * 16 + j) * (long long)ldc + (ocBase + ni * 16);
                if constexpr (FUSED) {
                    float gv = acc0[mi][ni][j];
                    float uv = acc1[mi][ni][j];
                    float v = (gv / (1.f + __expf(-gv))) * uv;  // silu(g)*u
                    ((f16*)Cv)[idx] = (f16)v;
                } else {
                    ((float*)Cv)[idx] = acc0[mi][ni][j];
                }
            }
}

extern "C" void kernel_launch(void* const* d_in, const int* in_sizes, int n_in,
                              void* d_out, int out_size, void* d_ws, size_t ws_size,
                              hipStream_t stream) {
    const float* x  = (const float*)d_in[0];   // [T, HD] f32 (fp16-exact values)
    const float* Wg = (const float*)d_in[1];   // [M, HD] f32
    const float* Wu = (const float*)d_in[2];   // [M, HD] f32
    const float* Wd = (const float*)d_in[3];   // [HD, M] f32
    float* out = (float*)d_out;                // [T, HD] f32
    f16* H = (f16*)d_ws;                       // [chunk, M] fp16 intermediate

    const int HD = 4096;
    const int T  = in_sizes[0] / HD;           // 8192
    const int M  = in_sizes[1] / HD;           // 14336

    // chunk rows of fp16 [M] must fit in ws_size
    const long long bytesPerRow = (long long)M * sizeof(f16);
    const long long maxRows = (ws_size > 0) ? (long long)(ws_size / bytesPerRow) : 0;
    int chunk = (int)((maxRows / 128) * 128);
    if (chunk > T) chunk = T;
    if (chunk <= 0) {
        fill_sentinel_f32<<<1024, 256, 0, stream>>>(out, (long long)out_size);
        return;
    }

    for (int t0 = 0; t0 < T; t0 += chunk) {
        int rows = (T - t0 < chunk) ? (T - t0) : chunk;
        int nRow1 = rows / 128, nCol1 = M / 128;
        mlp_gemm<true><<<dim3(nRow1 * nCol1), dim3(256), 0, stream>>>(
            (const void*)(x + (size_t)t0 * HD), Wg, Wu, (void*)H,
            HD, M, nRow1, nCol1);
        int nRow2 = rows / 128, nCol2 = HD / 128;
        mlp_gemm<false><<<dim3(nRow2 * nCol2), dim3(256), 0, stream>>>(
            (const void*)H, Wd, nullptr, (void*)(out + (size_t)t0 * HD),
            M, HD, nRow2, nCol2);
    }
}

// Round 7
// 5891.876 us; speedup vs baseline: 1.4043x; 1.4043x over previous
//
#include <hip/hip_runtime.h>

typedef _Float16 f16;
typedef _Float16 f16x8 __attribute__((ext_vector_type(8)));
typedef float f32x4 __attribute__((ext_vector_type(4)));

__device__ __forceinline__ f16x8 cvt8(f32x4 lo, f32x4 hi) {
    f16x8 h;
    h[0] = (f16)lo[0]; h[1] = (f16)lo[1]; h[2] = (f16)lo[2]; h[3] = (f16)lo[3];
    h[4] = (f16)hi[0]; h[5] = (f16)hi[1]; h[6] = (f16)hi[2]; h[7] = (f16)hi[3];
    return h;
}

// f32 -> f16 elementwise convert (values are fp16-exact, so lossless).
__global__ __launch_bounds__(256)
void cvt_f32_f16(const float* __restrict__ in, f16* __restrict__ out, long long n) {
    long long i = ((long long)blockIdx.x * 256 + threadIdx.x) * 8;
    const long long stride = (long long)gridDim.x * 256 * 8;
    for (; i < n; i += stride) {
        f32x4 a = *(const f32x4*)(in + i);
        f32x4 b = *(const f32x4*)(in + i + 4);
        *(f16x8*)(out + i) = cvt8(a, b);
    }
}

__global__ void fill_sentinel_f32(float* __restrict__ out, long long n) {
    long long i = (long long)blockIdx.x * blockDim.x + threadIdx.x;
    long long stride = (long long)gridDim.x * blockDim.x;
    for (; i < n; i += stride) out[i] = 1.0f;
}

template<bool IS16>
__device__ __forceinline__ f16x8 load8(const char* p) {
    if constexpr (IS16) {
        return *(const f16x8*)p;
    } else {
        const float* f = (const float*)p;
        return cvt8(*(const f32x4*)f, *(const f32x4*)(f + 4));
    }
}

// NT GEMM: A [rows,K], B [cols,K]; C[r,c] = sum_k A[r,k]*B[c,k]. fp16 MFMA, f32 acc.
// A16/B16: operand element type is f16 (else f32, converted while staging).
// FUSED: B1 second weight; epilogue writes silu(gate)*up as f16. Else C = f32.
// 128x128 tile, BK=32, 256 threads (4 waves 2x2), wave -> 64x64 out.
// Block order: supergroups of RG row-blocks; within a supergroup col-outer,
// row-inner => weight col-panel L2-resident, A row-panel L3-resident.
template<bool FUSED, bool A16, bool B16>
__global__ __launch_bounds__(256)
void mlp_gemm(const void* __restrict__ Av, const void* __restrict__ B0v,
              const void* __restrict__ B1v, void* __restrict__ Cv,
              int K, int ldc, int nRow, int nCol, int RG) {
    __shared__ __align__(16) f16 smA[128 * 32];
    __shared__ __align__(16) f16 smB0[128 * 32];
    __shared__ __align__(16) f16 smB1[FUSED ? 128 * 32 : 8];

    // ---- block remap ----
    const int lin   = blockIdx.x;
    const int perSg = RG * nCol;
    const int sg    = lin / perSg;
    const int rem   = lin - sg * perSg;
    int rgIn = nRow - sg * RG; if (rgIn > RG) rgIn = RG;
    const int colB = rem / rgIn;
    const int rowB = sg * RG + (rem - colB * rgIn);

    const long long blockRow = (long long)rowB * 128;
    const long long blockCol = (long long)colB * 128;

    const int tid  = threadIdx.x;
    const int w    = tid >> 6;
    const int lane = tid & 63;
    const int waveM = w >> 1;
    const int waveN = w & 1;

    // ---- staging slots: slot=tid (+256); row=slot>>2, seg=slot&3 (8 elems) ----
    const int r0 = tid >> 2;
    const int s0 = tid & 3;
    const int szA = A16 ? 2 : 4;
    const int szB = B16 ? 2 : 4;
    const char* gA0  = (const char*)Av  + ((blockRow + r0)      * (long long)K + s0 * 8) * szA;
    const char* gA1  = (const char*)Av  + ((blockRow + r0 + 64) * (long long)K + s0 * 8) * szA;
    const char* gB00 = (const char*)B0v + ((blockCol + r0)      * (long long)K + s0 * 8) * szB;
    const char* gB01 = (const char*)B0v + ((blockCol + r0 + 64) * (long long)K + s0 * 8) * szB;
    const char* gB10 = FUSED ? (const char*)B1v + ((blockCol + r0)      * (long long)K + s0 * 8) * szB : nullptr;
    const char* gB11 = FUSED ? (const char*)B1v + ((blockCol + r0 + 64) * (long long)K + s0 * 8) * szB : nullptr;

    const int off0 = tid * 8;       // f16 elem offset in [128][32] tile
    const int off1 = off0 + 2048;   // +64 rows

    // ---- fragment offsets (16x16x32: row=lane&15, k=(lane>>4)*8) ----
    const int fr = lane & 15;
    const int fk = (lane >> 4) * 8;
    int offA[4], offB[4];
#pragma unroll
    for (int i = 0; i < 4; ++i) {
        offA[i] = (waveM * 64 + i * 16 + fr) * 32 + fk;
        offB[i] = (waveN * 64 + i * 16 + fr) * 32 + fk;
    }

    f32x4 acc0[4][4];
    f32x4 acc1[4][4];
#pragma unroll
    for (int mi = 0; mi < 4; ++mi)
#pragma unroll
        for (int ni = 0; ni < 4; ++ni) {
            acc0[mi][ni] = (f32x4){0.f, 0.f, 0.f, 0.f};
            if constexpr (FUSED) acc1[mi][ni] = (f32x4){0.f, 0.f, 0.f, 0.f};
        }

    const int ksteps = K >> 5;
    for (int kt = 0; kt < ksteps; ++kt) {
        // issue global loads (latency hides under previous MFMA block)
        f16x8 vA0  = load8<A16>(gA0);
        f16x8 vA1  = load8<A16>(gA1);
        f16x8 vB00 = load8<B16>(gB00);
        f16x8 vB01 = load8<B16>(gB01);
        f16x8 vB10, vB11;
        if constexpr (FUSED) {
            vB10 = load8<B16>(gB10);
            vB11 = load8<B16>(gB11);
        }
        gA0 += 32 * szA; gA1 += 32 * szA;
        gB00 += 32 * szB; gB01 += 32 * szB;
        if constexpr (FUSED) { gB10 += 32 * szB; gB11 += 32 * szB; }

        __syncthreads();   // previous iteration's LDS reads complete

        *(f16x8*)(smA  + off0) = vA0;
        *(f16x8*)(smA  + off1) = vA1;
        *(f16x8*)(smB0 + off0) = vB00;
        *(f16x8*)(smB0 + off1) = vB01;
        if constexpr (FUSED) {
            *(f16x8*)(smB1 + off0) = vB10;
            *(f16x8*)(smB1 + off1) = vB11;
        }

        __syncthreads();   // tiles visible

        f16x8 aF[4], bF[4], b1F[4];
#pragma unroll
        for (int i = 0; i < 4; ++i) aF[i] = *(const f16x8*)(smA + offA[i]);
#pragma unroll
        for (int i = 0; i < 4; ++i) bF[i] = *(const f16x8*)(smB0 + offB[i]);
        if constexpr (FUSED) {
#pragma unroll
            for (int i = 0; i < 4; ++i) b1F[i] = *(const f16x8*)(smB1 + offB[i]);
        }

#pragma unroll
        for (int mi = 0; mi < 4; ++mi)
#pragma unroll
            for (int ni = 0; ni < 4; ++ni) {
                acc0[mi][ni] = __builtin_amdgcn_mfma_f32_16x16x32_f16(
                    aF[mi], bF[ni], acc0[mi][ni], 0, 0, 0);
                if constexpr (FUSED)
                    acc1[mi][ni] = __builtin_amdgcn_mfma_f32_16x16x32_f16(
                        aF[mi], b1F[ni], acc1[mi][ni], 0, 0, 0);
            }
    }

    // ---- epilogue: C/D layout col=lane&15, row=(lane>>4)*4+j ----
    const long long orBase = blockRow + waveM * 64 + ((lane >> 4) * 4);
    const long long ocBase = blockCol + waveN * 64 + fr;
#pragma unroll
    for (int mi = 0; mi < 4; ++mi)
#pragma unroll
        for (int ni = 0; ni < 4; ++ni)
#pragma unroll
            for (int j = 0; j < 4; ++j) {
                const long long idx =
                    (orBase + mi * 16 + j) * (long long)ldc + (ocBase + ni * 16);
                if constexpr (FUSED) {
                    float gv = acc0[mi][ni][j];
                    float uv = acc1[mi][ni][j];
                    float v = (gv / (1.f + __expf(-gv))) * uv;  // silu(g)*u
                    ((f16*)Cv)[idx] = (f16)v;
                } else {
                    ((float*)Cv)[idx] = acc0[mi][ni][j];
                }
            }
}

extern "C" void kernel_launch(void* const* d_in, const int* in_sizes, int n_in,
                              void* d_out, int out_size, void* d_ws, size_t ws_size,
                              hipStream_t stream) {
    const float* x  = (const float*)d_in[0];   // [T, HD] f32 (fp16-exact)
    const float* Wg = (const float*)d_in[1];   // [M, HD] f32
    const float* Wu = (const float*)d_in[2];   // [M, HD] f32
    const float* Wd = (const float*)d_in[3];   // [HD, M] f32
    float* out = (float*)d_out;                // [T, HD] f32

    const int HD = 4096;
    const int T  = in_sizes[0] / HD;           // 8192
    const int M  = in_sizes[1] / HD;           // 14336

    const long long nW = (long long)M * HD;    // elems per weight
    const long long nX = (long long)T * HD;
    const size_t wBytes = (size_t)nW * 2;      // 117.4 MB
    const size_t xBytes = (size_t)nX * 2;      // 67.1 MB
    const size_t hRow   = (size_t)M * 2;       // bytes per H row
    const size_t minH   = 128 * hRow;          // 3.67 MB

    // carve d_ws: [Wg16][Wu16][Wd16][X16?][H...]
    char* p = (char*)d_ws;
    size_t rem = ws_size;
    f16 *Wg16 = nullptr, *Wu16 = nullptr, *Wd16 = nullptr, *X16 = nullptr;
    bool wf16 = false, xf16 = false;
    if (rem >= 3 * wBytes + minH) {
        Wg16 = (f16*)p; p += wBytes;
        Wu16 = (f16*)p; p += wBytes;
        Wd16 = (f16*)p; p += wBytes;
        rem -= 3 * wBytes;
        wf16 = true;
        if (rem >= xBytes + minH) {
            X16 = (f16*)p; p += xBytes; rem -= xBytes; xf16 = true;
        }
    }
    f16* H = (f16*)p;
    long long maxRows = (long long)(rem / hRow);
    int chunk = (int)((maxRows / 128) * 128);
    if (chunk > T) chunk = T;
    if (chunk <= 0) {
        fill_sentinel_f32<<<1024, 256, 0, stream>>>(out, (long long)out_size);
        return;
    }

    if (wf16) {
        cvt_f32_f16<<<2048, 256, 0, stream>>>(Wg, Wg16, nW);
        cvt_f32_f16<<<2048, 256, 0, stream>>>(Wu, Wu16, nW);
        cvt_f32_f16<<<2048, 256, 0, stream>>>(Wd, Wd16, nW);
    }
    if (xf16) cvt_f32_f16<<<2048, 256, 0, stream>>>(x, X16, nX);

    for (int t0 = 0; t0 < T; t0 += chunk) {
        int rows = (T - t0 < chunk) ? (T - t0) : chunk;
        int nRow = rows / 128;
        // ---- GEMM1: [rows,HD] x [M,HD]^T -> H [rows,M] (fused silu*up) ----
        {
            int nCol = M / 128;
            dim3 grid(nRow * nCol);
            int RG = nRow;   // pure col-major: x chunk L3-resident, W streamed once
            if (xf16)
                mlp_gemm<true, true, true><<<grid, 256, 0, stream>>>(
                    X16 + (size_t)t0 * HD, Wg16, Wu16, H, HD, M, nRow, nCol, RG);
            else if (wf16)
                mlp_gemm<true, false, true><<<grid, 256, 0, stream>>>(
                    x + (size_t)t0 * HD, Wg16, Wu16, H, HD, M, nRow, nCol, RG);
            else
                mlp_gemm<true, false, false><<<grid, 256, 0, stream>>>(
                    x + (size_t)t0 * HD, Wg, Wu, H, HD, M, nRow, nCol, RG);
        }
        // ---- GEMM2: H [rows,M] x [HD,M]^T -> out [rows,HD] ----
        {
            int nCol = HD / 128;
            dim3 grid(nRow * nCol);
            int RG = (nRow < 32) ? nRow : 32;  // H panel <=117MB L3-resident
            if (wf16)
                mlp_gemm<false, true, true><<<grid, 256, 0, stream>>>(
                    H, Wd16, nullptr, out + (size_t)t0 * HD, M, HD, nRow, nCol, RG);
            else
                mlp_gemm<false, true, false><<<grid, 256, 0, stream>>>(
                    H, Wd, nullptr, out + (size_t)t0 * HD, M, HD, nRow, nCol, RG);
        }
    }
}

// Round 8
// 2948.152 us; speedup vs baseline: 2.8065x; 1.9985x over previous
//
#include <hip/hip_runtime.h>

typedef _Float16 f16;
typedef _Float16 f16x8 __attribute__((ext_vector_type(8)));
typedef float f32x4 __attribute__((ext_vector_type(4)));

__device__ __forceinline__ f16x8 cvt8(f32x4 lo, f32x4 hi) {
    f16x8 h;
    h[0] = (f16)lo[0]; h[1] = (f16)lo[1]; h[2] = (f16)lo[2]; h[3] = (f16)lo[3];
    h[4] = (f16)hi[0]; h[5] = (f16)hi[1]; h[6] = (f16)hi[2]; h[7] = (f16)hi[3];
    return h;
}

// f32 -> f16 elementwise convert (values are fp16-exact, so lossless).
__global__ __launch_bounds__(256)
void cvt_f32_f16(const float* __restrict__ in, f16* __restrict__ out, long long n) {
    long long i = ((long long)blockIdx.x * 256 + threadIdx.x) * 8;
    const long long stride = (long long)gridDim.x * 256 * 8;
    for (; i < n; i += stride) {
        f32x4 a = *(const f32x4*)(in + i);
        f32x4 b = *(const f32x4*)(in + i + 4);
        *(f16x8*)(out + i) = cvt8(a, b);
    }
}

__global__ void fill_sentinel_f32(float* __restrict__ out, long long n) {
    long long i = (long long)blockIdx.x * blockDim.x + threadIdx.x;
    long long stride = (long long)gridDim.x * blockDim.x;
    for (; i < n; i += stride) out[i] = 1.0f;
}

// Async global->LDS, 16B/lane. LDS dest = wave-uniform base + lane*16.
__device__ __forceinline__ void gload_lds16(const f16* g, f16* l) {
    __builtin_amdgcn_global_load_lds(
        (const __attribute__((address_space(1))) unsigned int*)(unsigned long long)g,
        (__attribute__((address_space(3))) unsigned int*)(unsigned int)(unsigned long long)l,
        16, 0, 0);
}

// ============================== fast path (all-f16) ==========================
// NT GEMM: A [rows,K] f16, B [cols,K] f16; C[r,c]=sum_k A[r,k]*B[c,k].
// 128x128 tile, BK=64, 512 threads (8 waves: 2M x 4N), wave tile 64x32.
// global_load_lds width-16 staging; XOR swizzle (elem col ^= (row&7)<<3)
// applied on the PRE-SWIZZLED GLOBAL SOURCE (LDS dest linear) and on ds_read.
// FUSED: B1 = second weight; epilogue writes silu(gate)*up as f16. Else C=f32.
template<bool FUSED>
__global__ __launch_bounds__(512)
void mlp_gemm16(const f16* __restrict__ A, const f16* __restrict__ B0,
                const f16* __restrict__ B1, void* __restrict__ Cv,
                int K, int ldc, int nRow, int nCol, int RG) {
    __shared__ __align__(16) f16 smA[128 * 64];
    __shared__ __align__(16) f16 smB0[128 * 64];
    __shared__ __align__(16) f16 smB1[FUSED ? 128 * 64 : 8];

    // ---- block remap: supergroups of RG row-blocks, col-outer within ----
    const int lin   = blockIdx.x;
    const int perSg = RG * nCol;
    const int sg    = lin / perSg;
    const int rem   = lin - sg * perSg;
    int rgIn = nRow - sg * RG; if (rgIn > RG) rgIn = RG;
    const int colB = rem / rgIn;
    const int rowB = sg * RG + (rem - colB * rgIn);

    const long long blockRow = (long long)rowB * 128;
    const long long blockCol = (long long)colB * 128;

    const int tid  = threadIdx.x;
    const int w    = tid >> 6;      // 0..7
    const int lane = tid & 63;
    const int waveM = w >> 2;       // 0..1 -> 64 rows
    const int waveN = w & 3;        // 0..3 -> 32 cols

    // ---- staging geometry (per 128x64 tile, 2 issues of 64 rows) ----
    // dest (linear): row dr = i*64 + w*8 + (lane>>3), col elems de = (lane&7)*8
    // source col pre-swizzled: se = de ^ ((dr&7)<<3), dr&7 == lane>>3
    const int drw = w * 8 + (lane >> 3);
    const int se  = ((lane & 7) << 3) ^ ((lane >> 3) << 3);
    const f16* gA0  = A  + (blockRow + drw) * (long long)K + se;
    const f16* gA1  = gA0 + 64 * (long long)K;
    const f16* gB00 = B0 + (blockCol + drw) * (long long)K + se;
    const f16* gB01 = gB00 + 64 * (long long)K;
    const f16* gB10 = FUSED ? (B1 + (blockCol + drw) * (long long)K + se) : nullptr;
    const f16* gB11 = FUSED ? (gB10 + 64 * (long long)K) : nullptr;

    f16* lA0  = smA  + w * 512;          // wave-uniform LDS bases (elems)
    f16* lA1  = smA  + 4096 + w * 512;   // issue 1: +64 rows
    f16* lB00 = smB0 + w * 512;
    f16* lB01 = smB0 + 4096 + w * 512;
    f16* lB10 = smB1 + w * 512;
    f16* lB11 = smB1 + 4096 + w * 512;

    // ---- fragment read offsets (16x16x32: row=lane&15, k=(lane>>4)*8) ----
    const int fr = lane & 15;
    const int hi = lane >> 4;            // 0..3
    const int swz = (fr & 7) << 3;       // read-side XOR (elems)
    int offA[2][4], offB[2][2];
#pragma unroll
    for (int ks = 0; ks < 2; ++ks) {
        const int kterm = (ks * 32 + hi * 8) ^ swz;
#pragma unroll
        for (int i = 0; i < 4; ++i)
            offA[ks][i] = (waveM * 64 + i * 16 + fr) * 64 + kterm;
#pragma unroll
        for (int n = 0; n < 2; ++n)
            offB[ks][n] = (waveN * 32 + n * 16 + fr) * 64 + kterm;
    }

    f32x4 acc0[4][2];
    f32x4 acc1[4][2];
#pragma unroll
    for (int mi = 0; mi < 4; ++mi)
#pragma unroll
        for (int ni = 0; ni < 2; ++ni) {
            acc0[mi][ni] = (f32x4){0.f, 0.f, 0.f, 0.f};
            if constexpr (FUSED) acc1[mi][ni] = (f32x4){0.f, 0.f, 0.f, 0.f};
        }

    const int ksteps = K >> 6;
    for (int kt = 0; kt < ksteps; ++kt) {
        gload_lds16(gA0,  lA0);
        gload_lds16(gA1,  lA1);
        gload_lds16(gB00, lB00);
        gload_lds16(gB01, lB01);
        if constexpr (FUSED) {
            gload_lds16(gB10, lB10);
            gload_lds16(gB11, lB11);
        }
        gA0 += 64; gA1 += 64; gB00 += 64; gB01 += 64;
        if constexpr (FUSED) { gB10 += 64; gB11 += 64; }

        __syncthreads();   // drains vmcnt: tiles valid

#pragma unroll
        for (int ks = 0; ks < 2; ++ks) {
            f16x8 aF[4], bF[2], b1F[2];
#pragma unroll
            for (int i = 0; i < 4; ++i) aF[i] = *(const f16x8*)(smA + offA[ks][i]);
#pragma unroll
            for (int n = 0; n < 2; ++n) bF[n] = *(const f16x8*)(smB0 + offB[ks][n]);
            if constexpr (FUSED) {
#pragma unroll
                for (int n = 0; n < 2; ++n) b1F[n] = *(const f16x8*)(smB1 + offB[ks][n]);
            }
#pragma unroll
            for (int mi = 0; mi < 4; ++mi)
#pragma unroll
                for (int ni = 0; ni < 2; ++ni) {
                    acc0[mi][ni] = __builtin_amdgcn_mfma_f32_16x16x32_f16(
                        aF[mi], bF[ni], acc0[mi][ni], 0, 0, 0);
                    if constexpr (FUSED)
                        acc1[mi][ni] = __builtin_amdgcn_mfma_f32_16x16x32_f16(
                            aF[mi], b1F[ni], acc1[mi][ni], 0, 0, 0);
                }
        }

        __syncthreads();   // protect tiles until all waves done reading
    }

    // ---- epilogue: C/D layout col=lane&15, row=(lane>>4)*4+j ----
    const long long orBase = blockRow + waveM * 64 + hi * 4;
    const long long ocBase = blockCol + waveN * 32 + fr;
#pragma unroll
    for (int mi = 0; mi < 4; ++mi)
#pragma unroll
        for (int ni = 0; ni < 2; ++ni)
#pragma unroll
            for (int j = 0; j < 4; ++j) {
                const long long idx =
                    (orBase + mi * 16 + j) * (long long)ldc + (ocBase + ni * 16);
                if constexpr (FUSED) {
                    float gv = acc0[mi][ni][j];
                    float uv = acc1[mi][ni][j];
                    float v = (gv / (1.f + __expf(-gv))) * uv;  // silu(g)*u
                    ((f16*)Cv)[idx] = (f16)v;
                } else {
                    ((float*)Cv)[idx] = acc0[mi][ni][j];
                }
            }
}

// ======================= fallback path (f32 operands) ========================
// Round-7 reg-staged kernel, kept only for the (unobserved) tiny-ws case.
template<bool IS16>
__device__ __forceinline__ f16x8 load8(const char* p) {
    if constexpr (IS16) return *(const f16x8*)p;
    const float* f = (const float*)p;
    return cvt8(*(const f32x4*)f, *(const f32x4*)(f + 4));
}

template<bool FUSED, bool A16, bool B16>
__global__ __launch_bounds__(256)
void mlp_gemm(const void* __restrict__ Av, const void* __restrict__ B0v,
              const void* __restrict__ B1v, void* __restrict__ Cv,
              int K, int ldc, int nRow, int nCol, int RG) {
    __shared__ __align__(16) f16 smA[128 * 32];
    __shared__ __align__(16) f16 smB0[128 * 32];
    __shared__ __align__(16) f16 smB1[FUSED ? 128 * 32 : 8];

    const int lin   = blockIdx.x;
    const int perSg = RG * nCol;
    const int sg    = lin / perSg;
    const int rem   = lin - sg * perSg;
    int rgIn = nRow - sg * RG; if (rgIn > RG) rgIn = RG;
    const int colB = rem / rgIn;
    const int rowB = sg * RG + (rem - colB * rgIn);

    const long long blockRow = (long long)rowB * 128;
    const long long blockCol = (long long)colB * 128;

    const int tid  = threadIdx.x;
    const int w    = tid >> 6;
    const int lane = tid & 63;
    const int waveM = w >> 1;
    const int waveN = w & 1;

    const int r0 = tid >> 2;
    const int s0 = tid & 3;
    const int szA = A16 ? 2 : 4;
    const int szB = B16 ? 2 : 4;
    const char* gA0  = (const char*)Av  + ((blockRow + r0)      * (long long)K + s0 * 8) * szA;
    const char* gA1  = (const char*)Av  + ((blockRow + r0 + 64) * (long long)K + s0 * 8) * szA;
    const char* gB00 = (const char*)B0v + ((blockCol + r0)      * (long long)K + s0 * 8) * szB;
    const char* gB01 = (const char*)B0v + ((blockCol + r0 + 64) * (long long)K + s0 * 8) * szB;
    const char* gB10 = FUSED ? (const char*)B1v + ((blockCol + r0)      * (long long)K + s0 * 8) * szB : nullptr;
    const char* gB11 = FUSED ? (const char*)B1v + ((blockCol + r0 + 64) * (long long)K + s0 * 8) * szB : nullptr;

    const int off0 = tid * 8;
    const int off1 = off0 + 2048;

    const int fr = lane & 15;
    const int fk = (lane >> 4) * 8;
    int offA[4], offB[4];
#pragma unroll
    for (int i = 0; i < 4; ++i) {
        offA[i] = (waveM * 64 + i * 16 + fr) * 32 + fk;
        offB[i] = (waveN * 64 + i * 16 + fr) * 32 + fk;
    }

    f32x4 acc0[4][4];
    f32x4 acc1[4][4];
#pragma unroll
    for (int mi = 0; mi < 4; ++mi)
#pragma unroll
        for (int ni = 0; ni < 4; ++ni) {
            acc0[mi][ni] = (f32x4){0.f, 0.f, 0.f, 0.f};
            if constexpr (FUSED) acc1[mi][ni] = (f32x4){0.f, 0.f, 0.f, 0.f};
        }

    const int ksteps = K >> 5;
    for (int kt = 0; kt < ksteps; ++kt) {
        f16x8 vA0  = load8<A16>(gA0);
        f16x8 vA1  = load8<A16>(gA1);
        f16x8 vB00 = load8<B16>(gB00);
        f16x8 vB01 = load8<B16>(gB01);
        f16x8 vB10, vB11;
        if constexpr (FUSED) {
            vB10 = load8<B16>(gB10);
            vB11 = load8<B16>(gB11);
        }
        gA0 += 32 * szA; gA1 += 32 * szA;
        gB00 += 32 * szB; gB01 += 32 * szB;
        if constexpr (FUSED) { gB10 += 32 * szB; gB11 += 32 * szB; }

        __syncthreads();

        *(f16x8*)(smA  + off0) = vA0;
        *(f16x8*)(smA  + off1) = vA1;
        *(f16x8*)(smB0 + off0) = vB00;
        *(f16x8*)(smB0 + off1) = vB01;
        if constexpr (FUSED) {
            *(f16x8*)(smB1 + off0) = vB10;
            *(f16x8*)(smB1 + off1) = vB11;
        }

        __syncthreads();

        f16x8 aF[4], bF[4], b1F[4];
#pragma unroll
        for (int i = 0; i < 4; ++i) aF[i] = *(const f16x8*)(smA + offA[i]);
#pragma unroll
        for (int i = 0; i < 4; ++i) bF[i] = *(const f16x8*)(smB0 + offB[i]);
        if constexpr (FUSED) {
#pragma unroll
            for (int i = 0; i < 4; ++i) b1F[i] = *(const f16x8*)(smB1 + offB[i]);
        }

#pragma unroll
        for (int mi = 0; mi < 4; ++mi)
#pragma unroll
            for (int ni = 0; ni < 4; ++ni) {
                acc0[mi][ni] = __builtin_amdgcn_mfma_f32_16x16x32_f16(
                    aF[mi], bF[ni], acc0[mi][ni], 0, 0, 0);
                if constexpr (FUSED)
                    acc1[mi][ni] = __builtin_amdgcn_mfma_f32_16x16x32_f16(
                        aF[mi], b1F[ni], acc1[mi][ni], 0, 0, 0);
            }
    }

    const long long orBase = blockRow + waveM * 64 + ((lane >> 4) * 4);
    const long long ocBase = blockCol + waveN * 64 + fr;
#pragma unroll
    for (int mi = 0; mi < 4; ++mi)
#pragma unroll
        for (int ni = 0; ni < 4; ++ni)
#pragma unroll
            for (int j = 0; j < 4; ++j) {
                const long long idx =
                    (orBase + mi * 16 + j) * (long long)ldc + (ocBase + ni * 16);
                if constexpr (FUSED) {
                    float gv = acc0[mi][ni][j];
                    float uv = acc1[mi][ni][j];
                    float v = (gv / (1.f + __expf(-gv))) * uv;
                    ((f16*)Cv)[idx] = (f16)v;
                } else {
                    ((float*)Cv)[idx] = acc0[mi][ni][j];
                }
            }
}

extern "C" void kernel_launch(void* const* d_in, const int* in_sizes, int n_in,
                              void* d_out, int out_size, void* d_ws, size_t ws_size,
                              hipStream_t stream) {
    const float* x  = (const float*)d_in[0];   // [T, HD] f32 (fp16-exact)
    const float* Wg = (const float*)d_in[1];   // [M, HD] f32
    const float* Wu = (const float*)d_in[2];   // [M, HD] f32
    const float* Wd = (const float*)d_in[3];   // [HD, M] f32
    float* out = (float*)d_out;                // [T, HD] f32

    const int HD = 4096;
    const int T  = in_sizes[0] / HD;           // 8192
    const int M  = in_sizes[1] / HD;           // 14336

    const long long nW = (long long)M * HD;
    const long long nX = (long long)T * HD;
    const size_t wBytes = (size_t)nW * 2;      // 117.4 MB
    const size_t xBytes = (size_t)nX * 2;      // 67.1 MB
    const size_t hRow   = (size_t)M * 2;
    const size_t minH   = 128 * hRow;          // 3.67 MB

    // carve d_ws: [Wg16][Wu16][Wd16][X16?][H...]
    char* p = (char*)d_ws;
    size_t rem = ws_size;
    f16 *Wg16 = nullptr, *Wu16 = nullptr, *Wd16 = nullptr, *X16 = nullptr;
    bool wf16 = false, xf16 = false;
    if (rem >= 3 * wBytes + minH) {
        Wg16 = (f16*)p; p += wBytes;
        Wu16 = (f16*)p; p += wBytes;
        Wd16 = (f16*)p; p += wBytes;
        rem -= 3 * wBytes;
        wf16 = true;
        if (rem >= xBytes + minH) {
            X16 = (f16*)p; p += xBytes; rem -= xBytes; xf16 = true;
        }
    }
    f16* H = (f16*)p;
    long long maxRows = (long long)(rem / hRow);
    int chunk = (int)((maxRows / 128) * 128);
    if (chunk > T) chunk = T;
    if (chunk <= 0) {
        fill_sentinel_f32<<<1024, 256, 0, stream>>>(out, (long long)out_size);
        return;
    }

    if (wf16) {
        cvt_f32_f16<<<2048, 256, 0, stream>>>(Wg, Wg16, nW);
        cvt_f32_f16<<<2048, 256, 0, stream>>>(Wu, Wu16, nW);
        cvt_f32_f16<<<2048, 256, 0, stream>>>(Wd, Wd16, nW);
    }
    if (xf16) cvt_f32_f16<<<2048, 256, 0, stream>>>(x, X16, nX);

    for (int t0 = 0; t0 < T; t0 += chunk) {
        int rows = (T - t0 < chunk) ? (T - t0) : chunk;
        int nRow = rows / 128;
        // ---- GEMM1: x [rows,HD] @ {Wg,Wu} -> H [rows,M] (silu*up fused) ----
        {
            int nCol = M / 128;
            dim3 grid(nRow * nCol);
            int RG = nRow;   // col-outer: x chunk L3-resident, W streamed once
            if (xf16)
                mlp_gemm16<true><<<grid, 512, 0, stream>>>(
                    X16 + (size_t)t0 * HD, Wg16, Wu16, H, HD, M, nRow, nCol, RG);
            else if (wf16)
                mlp_gemm<true, false, true><<<grid, 256, 0, stream>>>(
                    x + (size_t)t0 * HD, Wg16, Wu16, H, HD, M, nRow, nCol, RG);
            else
                mlp_gemm<true, false, false><<<grid, 256, 0, stream>>>(
                    x + (size_t)t0 * HD, Wg, Wu, H, HD, M, nRow, nCol, RG);
        }
        // ---- GEMM2: H [rows,M] @ Wd -> out [rows,HD] ----
        {
            int nCol = HD / 128;
            dim3 grid(nRow * nCol);
            int RG = (nRow < 32) ? nRow : 32;
            if (wf16)
                mlp_gemm16<false><<<grid, 512, 0, stream>>>(
                    H, Wd16, nullptr, out + (size_t)t0 * HD, M, HD, nRow, nCol, RG);
            else
                mlp_gemm<false, true, false><<<grid, 256, 0, stream>>>(
                    H, Wd, nullptr, out + (size_t)t0 * HD, M, HD, nRow, nCol, RG);
        }
    }
}